// Round 2
// baseline (4202.666 us; speedup 1.0000x reference)
//
#include <hip/hip_runtime.h>

#define VSZ 32000
#define TT 1024
#define LL 1024

typedef float f32x4 __attribute__((ext_vector_type(4)));

// ---------- fast activations (f32, ~2ulp; gates are saturated so plenty) ----------
__device__ __forceinline__ float fast_sigmoid(float x){
  return __builtin_amdgcn_rcpf(1.0f + __expf(-x));
}
__device__ __forceinline__ float fast_tanh(float x){
  float e = __expf(2.0f*x);
  return 1.0f - 2.0f*__builtin_amdgcn_rcpf(e + 1.0f);
}

__device__ __forceinline__ float rl(float v, int l){
  return __uint_as_float((unsigned)__builtin_amdgcn_readlane((int)__float_as_uint(v), l));
}

// ---------- 15-lane GRU weight load: lane g*5+i owns gate (g,i) ----------
__device__ __forceinline__ void load_gru_w(const float* __restrict__ W,
                                           const float* __restrict__ U,
                                           const float* __restrict__ b,
                                           int lane, float Wr[5], float U1r[5], float U2r[5], float& bb)
{
  int g = lane / 5;
  int i = lane - g*5;
  bool okl = (lane < 15);
  int base = okl ? (g*25 + i*5) : 0;
  int bidx = okl ? (g*5 + i) : 0;
  #pragma unroll
  for (int j=0;j<5;j++){
    float w  = W[base + j];
    float u  = U[base + j];
    float u2 = U[50 + i*5 + j];
    Wr[j]  = okl ? w : 0.0f;
    U1r[j] = (okl && g < 2) ? u  : 0.0f;
    U2r[j] = (okl && g == 2) ? u2 : 0.0f;
  }
  bb = okl ? b[bidx] : 0.0f;
}

// ---------- kernel A: pre_all[t][k] = b[k] + W_en[k]@(x[t]@Eg_en.T)  (k = g*5+i, 15 used, padded 16) ----------
__global__ __launch_bounds__(256) void matmul_pre(const float* __restrict__ x,
                                                  const float* __restrict__ Eg_en,
                                                  const float* __restrict__ W,
                                                  const float* __restrict__ b,
                                                  float* __restrict__ pre_all)
{
  const int t = blockIdx.x;
  const int tid = threadIdx.x;
  const int lane = tid & 63, wave = tid >> 6;
  const f32x4* xr = (const f32x4*)(x + (size_t)t*VSZ);
  float acc[5] = {0,0,0,0,0};
  for (int j = tid; j < VSZ/4; j += 256){
    f32x4 xv = xr[j];
    #pragma unroll
    for (int h=0;h<5;h++){
      f32x4 ev = ((const f32x4*)(Eg_en + (size_t)h*VSZ))[j];
      acc[h] += xv.x*ev.x + xv.y*ev.y + xv.z*ev.z + xv.w*ev.w;
    }
  }
  #pragma unroll
  for (int m=1;m<64;m<<=1){
    #pragma unroll
    for (int h=0;h<5;h++) acc[h] += __shfl_xor(acc[h], m, 64);
  }
  __shared__ float part[4][5];
  __shared__ float xe_s[5];
  if (lane == 0){
    #pragma unroll
    for (int h=0;h<5;h++) part[wave][h] = acc[h];
  }
  __syncthreads();
  if (tid < 5) xe_s[tid] = part[0][tid] + part[1][tid] + part[2][tid] + part[3][tid];
  __syncthreads();
  if (tid < 15){
    int g = tid/5, i = tid - g*5;
    float p = b[g*5+i];
    #pragma unroll
    for (int j=0;j<5;j++) p += W[g*25 + i*5 + j] * xe_s[j];
    pre_all[t*16 + tid] = p;
  }
}

// ---------- kernel B: sequential encoder scan (1 wave) using pre_all; clears decoder slots ----------
__global__ void enc_kernel(const float* __restrict__ pre_all,
                           float* __restrict__ s_enc,
                           float* __restrict__ slots_f, // 2048 floats (8KB) to clear
                           const float* __restrict__ U)
{
  const int lane = threadIdx.x;
  for (int k = lane; k < 2048; k += 64) slots_f[k] = 0.0f;

  int g = lane/5, i = lane - g*5;
  bool okl = (lane < 15);
  float U1r[5], U2r[5];
  #pragma unroll
  for (int j=0;j<5;j++){
    int base = okl ? (g*25 + i*5) : 0;
    float u  = U[base + j];
    float u2 = U[50 + i*5 + j];
    U1r[j] = (okl && g < 2) ? u  : 0.0f;
    U2r[j] = (okl && g == 2) ? u2 : 0.0f;
  }

  float s[5] = {0,0,0,0,0};
  float pre = okl ? pre_all[lane] : 0.0f;
  for (int t=0; t<TT; t++){
    int tn = (t < TT-1) ? (t+1) : t;
    float nxt = okl ? pre_all[tn*16 + lane] : 0.0f;   // prefetch next step
    // step: acc = pre(=b+W@xe) + U1@s
    float a0 = U1r[0]*s[0] + U1r[1]*s[1];
    float a1 = U1r[2]*s[2] + U1r[3]*s[3];
    float acc = pre + a0 + a1 + U1r[4]*s[4];
    float zr = fast_sigmoid(acc);
    float rr[5];
    #pragma unroll
    for (int j=0;j<5;j++) rr[j] = rl(zr, 5+j);
    float acc2 = acc;
    #pragma unroll
    for (int j=0;j<5;j++) acc2 += U2r[j]*(s[j]*rr[j]);
    float cv = fast_tanh(acc2);
    #pragma unroll
    for (int j=0;j<5;j++){
      float zj = rl(zr, j);
      float cj = rl(cv, 10+j);
      s[j] = cj + zj*(s[j]-cj);
    }
    pre = nxt;
  }
  if (lane == 0){
    #pragma unroll
    for (int j=0;j<5;j++) s_enc[j] = s[j];
  }
}

// ---------- kernel C: decoder. 16 WGs x 256 thr; weights register-resident; ----------
// ---------- 64-slot self-tagged all-to-all through L3; out-store in poll shadow ----------
__global__ __launch_bounds__(256, 1) void dec_kernel(
    const float* __restrict__ Eg_en, const float* __restrict__ Eg_de,
    const float* __restrict__ cg_de,
    const float* __restrict__ W, const float* __restrict__ U, const float* __restrict__ b,
    const float* __restrict__ s_enc,
    unsigned long long* __restrict__ slots,   // [2 parities][64 slots][8 u64]
    float* __restrict__ out)
{
  const int wg = blockIdx.x;
  const int tid = threadIdx.x;
  const int lane = tid & 63;
  const int wave = tid >> 6;
  const int slot_id = wg*4 + wave;

  float Wr[5], U1r[5], U2r[5], bb;
  load_gru_w(W, U, b, lane, Wr, U1r, U2r, bb);

  const bool act = (tid < 250);              // 250*8 = 2000 v's per WG
  const int v0 = wg*2000 + tid*8;
  float de[8][5], en[5][8], cb[8];
  if (act){
    #pragma unroll
    for (int k=0;k<8;k++){
      #pragma unroll
      for (int j=0;j<5;j++) de[k][j] = Eg_de[(v0+k)*5 + j];
      cb[k] = cg_de[v0+k];
    }
    #pragma unroll
    for (int h=0;h<5;h++){
      #pragma unroll
      for (int k=0;k<8;k++) en[h][k] = Eg_en[h*VSZ + v0 + k];
    }
  } else {
    #pragma unroll
    for (int k=0;k<8;k++){
      cb[k] = 0.0f;
      #pragma unroll
      for (int j=0;j<5;j++) de[k][j] = 0.0f;
    }
    #pragma unroll
    for (int h=0;h<5;h++){
      #pragma unroll
      for (int k=0;k<8;k++) en[h][k] = 0.0f;
    }
  }

  float s[5];
  #pragma unroll
  for (int j=0;j<5;j++) s[j] = s_enc[j];

  for (int t=0; t<LL; t++){
    // --- u_v = relu(Eg_de[v]@s + c_v); partial xe ---
    float px[5] = {0,0,0,0,0};
    float o[8];
    #pragma unroll
    for (int k=0;k<8;k++){
      float u = cb[k];
      #pragma unroll
      for (int j=0;j<5;j++) u += de[k][j]*s[j];
      u = fmaxf(u, 0.0f);
      o[k] = u;
      #pragma unroll
      for (int h=0;h<5;h++) px[h] += u*en[h][k];
    }

    if (t == LL-1){
      if (act){
        f32x4* po = (f32x4*)(out + (size_t)t*VSZ + v0);
        f32x4 a = {o[0], o[1], o[2], o[3]};
        f32x4 bv = {o[4], o[5], o[6], o[7]};
        po[0] = a; po[1] = bv;
      }
      break;
    }

    // --- intra-wave reduce, then publish ASAP ---
    #pragma unroll
    for (int m=1;m<64;m<<=1){
      #pragma unroll
      for (int h=0;h<5;h++) px[h] += __shfl_xor(px[h], m, 64);
    }
    const unsigned long long tg = (unsigned long long)(t+1);
    if (lane == 0){
      unsigned long long* wp = slots + ((size_t)(t&1)*64 + slot_id)*8;
      #pragma unroll
      for (int j=0;j<5;j++)
        __hip_atomic_store(wp+j, (tg<<32) | (unsigned long long)__float_as_uint(px[j]),
                           __ATOMIC_RELAXED, __HIP_MEMORY_SCOPE_AGENT);
    }

    // --- out-row store lands in the poll-wait shadow ---
    if (act){
      f32x4* po = (f32x4*)(out + (size_t)t*VSZ + v0);
      f32x4 a = {o[0], o[1], o[2], o[3]};
      f32x4 bv = {o[4], o[5], o[6], o[7]};
      po[0] = a; po[1] = bv;
    }

    // --- s-only GRU precompute (overlaps store/poll latency) ---
    float p0 = U1r[0]*s[0] + U1r[1]*s[1];
    float p1 = U1r[2]*s[2] + U1r[3]*s[3];
    float us1 = bb + p0 + p1 + U1r[4]*s[4];   // b + U1@s  (z,r lanes; == b for c lanes)
    float u2s[5];
    #pragma unroll
    for (int j=0;j<5;j++) u2s[j] = U2r[j]*s[j]; // c lanes only (else 0)

    // --- poll all 64 slots (lane <-> slot), parity double-buffered ---
    const unsigned long long* rp = slots + ((size_t)(t&1)*64 + lane)*8;
    unsigned long long w0,w1,w2,w3,w4;
    for(;;){
      w0 = __hip_atomic_load(rp+0, __ATOMIC_RELAXED, __HIP_MEMORY_SCOPE_AGENT);
      w1 = __hip_atomic_load(rp+1, __ATOMIC_RELAXED, __HIP_MEMORY_SCOPE_AGENT);
      w2 = __hip_atomic_load(rp+2, __ATOMIC_RELAXED, __HIP_MEMORY_SCOPE_AGENT);
      w3 = __hip_atomic_load(rp+3, __ATOMIC_RELAXED, __HIP_MEMORY_SCOPE_AGENT);
      w4 = __hip_atomic_load(rp+4, __ATOMIC_RELAXED, __HIP_MEMORY_SCOPE_AGENT);
      bool ok = ((w0>>32)==tg) & ((w1>>32)==tg) & ((w2>>32)==tg)
              & ((w3>>32)==tg) & ((w4>>32)==tg);
      if (__all(ok)) break;
    }
    float xe[5];
    xe[0] = __uint_as_float((unsigned)w0);
    xe[1] = __uint_as_float((unsigned)w1);
    xe[2] = __uint_as_float((unsigned)w2);
    xe[3] = __uint_as_float((unsigned)w3);
    xe[4] = __uint_as_float((unsigned)w4);
    #pragma unroll
    for (int m=1;m<64;m<<=1){
      #pragma unroll
      for (int j=0;j<5;j++) xe[j] += __shfl_xor(xe[j], m, 64);
    }

    // --- trimmed GRU tail ---
    float t0 = Wr[0]*xe[0] + Wr[1]*xe[1];
    float t1 = Wr[2]*xe[2] + Wr[3]*xe[3];
    float acc = us1 + t0 + t1 + Wr[4]*xe[4];
    float zr = fast_sigmoid(acc);               // z lanes 0-4, r lanes 5-9
    float rr[5];
    #pragma unroll
    for (int j=0;j<5;j++) rr[j] = rl(zr, 5+j);
    float q0 = u2s[0]*rr[0] + u2s[1]*rr[1];
    float q1 = u2s[2]*rr[2] + u2s[3]*rr[3];
    float acc2 = acc + q0 + q1 + u2s[4]*rr[4];
    float cv = fast_tanh(acc2);                 // c lanes 10-14
    #pragma unroll
    for (int j=0;j<5;j++){
      float zj = rl(zr, j);
      float cj = rl(cv, 10+j);
      s[j] = cj + zj*(s[j]-cj);
    }
  }
}

extern "C" void kernel_launch(void* const* d_in, const int* in_sizes, int n_in,
                              void* d_out, int out_size, void* d_ws, size_t ws_size,
                              hipStream_t stream)
{
  const float* x     = (const float*)d_in[0];
  // d_in[1] = l (==1024), fixed by problem shape
  const float* Eg_en = (const float*)d_in[2];
  const float* Eg_de = (const float*)d_in[3];
  const float* cg_de = (const float*)d_in[4];
  const float* Wg_en = (const float*)d_in[5];
  const float* Ug_en = (const float*)d_in[6];
  const float* bg_en = (const float*)d_in[7];
  const float* Wg_de = (const float*)d_in[8];
  const float* Ug_de = (const float*)d_in[9];
  const float* bg_de = (const float*)d_in[10];
  float* out = (float*)d_out;

  float* ws      = (float*)d_ws;
  float* pre_all = ws;             // 1024*16 = 16384 floats
  float* s_enc   = ws + 16384;     // 5 floats (pad to 64)
  float* slots_f = ws + 16448;     // 2048 floats = 8KB: [2][64][8] u64
  unsigned long long* slots = (unsigned long long*)slots_f;

  matmul_pre<<<dim3(TT), dim3(256), 0, stream>>>(x, Eg_en, Wg_en, bg_en, pre_all);
  enc_kernel<<<dim3(1), dim3(64), 0, stream>>>(pre_all, s_enc, slots_f, Ug_en);
  dec_kernel<<<dim3(16), dim3(256), 0, stream>>>(Eg_en, Eg_de, cg_de,
                                                 Wg_de, Ug_de, bg_de,
                                                 s_enc, slots, out);
}

// Round 3
// 386.933 us; speedup vs baseline: 10.8615x; 10.8615x over previous
//
#include <hip/hip_runtime.h>

#define VSZ 32000
#define TT 1024
#define LL 1024

typedef float f32x4 __attribute__((ext_vector_type(4)));

// ---------- fast activations (f32; saturate EXACTLY to 0/1/±1 for |x| large) ----------
__device__ __forceinline__ float fast_sigmoid(float x){
  return __builtin_amdgcn_rcpf(1.0f + __expf(-x));
}
__device__ __forceinline__ float fast_tanh(float x){
  float e = __expf(2.0f*x);
  return 1.0f - 2.0f*__builtin_amdgcn_rcpf(e + 1.0f);
}

__device__ __forceinline__ float rl(float v, int l){
  return __uint_as_float((unsigned)__builtin_amdgcn_readlane((int)__float_as_uint(v), l));
}

// ---------- 15-lane GRU weight load: lane g*5+i owns gate (g,i) ----------
__device__ __forceinline__ void load_gru_w(const float* __restrict__ W,
                                           const float* __restrict__ U,
                                           const float* __restrict__ b,
                                           int lane, float Wr[5], float U1r[5], float U2r[5], float& bb)
{
  int g = lane / 5;
  int i = lane - g*5;
  bool okl = (lane < 15);
  int base = okl ? (g*25 + i*5) : 0;
  int bidx = okl ? (g*5 + i) : 0;
  #pragma unroll
  for (int j=0;j<5;j++){
    float w  = W[base + j];
    float u  = U[base + j];
    float u2 = U[50 + i*5 + j];
    Wr[j]  = okl ? w : 0.0f;
    U1r[j] = (okl && g < 2) ? u  : 0.0f;
    U2r[j] = (okl && g == 2) ? u2 : 0.0f;
  }
  bb = okl ? b[bidx] : 0.0f;
}

// exact-form GRU step: s' = z*s + (1-z)*c  (z==1.0 -> s'==s bitwise)
__device__ __forceinline__ void gru_step_exact(const float xe[5], float s[5], bool& conv,
                                               const float Wr[5], const float U1r[5],
                                               const float U2r[5], float bb)
{
  float acc = bb;
  #pragma unroll
  for (int j=0;j<5;j++) acc += Wr[j]*xe[j];
  #pragma unroll
  for (int j=0;j<5;j++) acc += U1r[j]*s[j];
  float zr = fast_sigmoid(acc);               // z lanes 0-4, r lanes 5-9
  float rr[5];
  #pragma unroll
  for (int j=0;j<5;j++) rr[j] = rl(zr, 5+j);
  float acc2 = acc;
  #pragma unroll
  for (int j=0;j<5;j++) acc2 += U2r[j]*(s[j]*rr[j]);
  float cv = fast_tanh(acc2);                 // c lanes 10-14
  conv = true;
  #pragma unroll
  for (int j=0;j<5;j++){
    float zj = rl(zr, j);
    float cj = rl(cv, 10+j);
    float ns = zj*s[j] + (1.0f - zj)*cj;
    conv = conv && (__float_as_uint(ns) == __float_as_uint(s[j]));
    s[j] = ns;
  }
}

// ---------- kernel A: pre_all[t][k] = b[k] + W_en[k]@(x[t]@Eg_en.T) ----------
__global__ __launch_bounds__(256) void matmul_pre(const float* __restrict__ x,
                                                  const float* __restrict__ Eg_en,
                                                  const float* __restrict__ W,
                                                  const float* __restrict__ b,
                                                  float* __restrict__ pre_all)
{
  const int t = blockIdx.x;
  const int tid = threadIdx.x;
  const int lane = tid & 63, wave = tid >> 6;
  const f32x4* xr = (const f32x4*)(x + (size_t)t*VSZ);
  float acc[5] = {0,0,0,0,0};
  for (int j = tid; j < VSZ/4; j += 256){
    f32x4 xv = xr[j];
    #pragma unroll
    for (int h=0;h<5;h++){
      f32x4 ev = ((const f32x4*)(Eg_en + (size_t)h*VSZ))[j];
      acc[h] += xv.x*ev.x + xv.y*ev.y + xv.z*ev.z + xv.w*ev.w;
    }
  }
  #pragma unroll
  for (int m=1;m<64;m<<=1){
    #pragma unroll
    for (int h=0;h<5;h++) acc[h] += __shfl_xor(acc[h], m, 64);
  }
  __shared__ float part[4][5];
  __shared__ float xe_s[5];
  if (lane == 0){
    #pragma unroll
    for (int h=0;h<5;h++) part[wave][h] = acc[h];
  }
  __syncthreads();
  if (tid < 5) xe_s[tid] = part[0][tid] + part[1][tid] + part[2][tid] + part[3][tid];
  __syncthreads();
  if (tid < 15){
    int g = tid/5, i = tid - g*5;
    float p = b[g*5+i];
    #pragma unroll
    for (int j=0;j<5;j++) p += W[g*25 + i*5 + j] * xe_s[j];
    pre_all[t*16 + tid] = p;
  }
}

// ---------- kernel B: sequential encoder scan (1 wave) using pre_all; clears decoder slots ----------
__global__ void enc_kernel(const float* __restrict__ pre_all,
                           float* __restrict__ s_enc,
                           float* __restrict__ slots_f, // 2048 floats (8KB) to clear
                           const float* __restrict__ U)
{
  const int lane = threadIdx.x;
  for (int k = lane; k < 2048; k += 64) slots_f[k] = 0.0f;

  int g = lane/5, i = lane - g*5;
  bool okl = (lane < 15);
  float U1r[5], U2r[5];
  #pragma unroll
  for (int j=0;j<5;j++){
    int base = okl ? (g*25 + i*5) : 0;
    float u  = U[base + j];
    float u2 = U[50 + i*5 + j];
    U1r[j] = (okl && g < 2) ? u  : 0.0f;
    U2r[j] = (okl && g == 2) ? u2 : 0.0f;
  }

  float s[5] = {0,0,0,0,0};
  float pre = okl ? pre_all[lane] : 0.0f;
  for (int t=0; t<TT; t++){
    int tn = (t < TT-1) ? (t+1) : t;
    float nxt = okl ? pre_all[tn*16 + lane] : 0.0f;   // prefetch next step
    float a0 = U1r[0]*s[0] + U1r[1]*s[1];
    float a1 = U1r[2]*s[2] + U1r[3]*s[3];
    float acc = pre + a0 + a1 + U1r[4]*s[4];
    float zr = fast_sigmoid(acc);
    float rr[5];
    #pragma unroll
    for (int j=0;j<5;j++) rr[j] = rl(zr, 5+j);
    float acc2 = acc;
    #pragma unroll
    for (int j=0;j<5;j++) acc2 += U2r[j]*(s[j]*rr[j]);
    float cv = fast_tanh(acc2);
    #pragma unroll
    for (int j=0;j<5;j++){
      float zj = rl(zr, j);
      float cj = rl(cv, 10+j);
      s[j] = zj*s[j] + (1.0f - zj)*cj;
    }
    pre = nxt;
  }
  if (lane == 0){
    #pragma unroll
    for (int j=0;j<5;j++) s_enc[j] = s[j];
  }
}

// ---------- kernel C: decoder with exact fixed-point early exit ----------
__global__ __launch_bounds__(256, 1) void dec_kernel(
    const float* __restrict__ Eg_en, const float* __restrict__ Eg_de,
    const float* __restrict__ cg_de,
    const float* __restrict__ W, const float* __restrict__ U, const float* __restrict__ b,
    const float* __restrict__ s_enc,
    unsigned long long* __restrict__ slots,   // [2 parities][64 slots][8 u64]
    float* __restrict__ out)
{
  const int wg = blockIdx.x;
  const int tid = threadIdx.x;
  const int lane = tid & 63;
  const int wave = tid >> 6;
  const int slot_id = wg*4 + wave;

  float Wr[5], U1r[5], U2r[5], bb;
  load_gru_w(W, U, b, lane, Wr, U1r, U2r, bb);

  const bool act = (tid < 250);              // 250*8 = 2000 v's per WG
  const int v0 = wg*2000 + tid*8;
  float de[8][5], en[5][8], cb[8];
  if (act){
    #pragma unroll
    for (int k=0;k<8;k++){
      #pragma unroll
      for (int j=0;j<5;j++) de[k][j] = Eg_de[(v0+k)*5 + j];
      cb[k] = cg_de[v0+k];
    }
    #pragma unroll
    for (int h=0;h<5;h++){
      #pragma unroll
      for (int k=0;k<8;k++) en[h][k] = Eg_en[h*VSZ + v0 + k];
    }
  } else {
    #pragma unroll
    for (int k=0;k<8;k++){
      cb[k] = 0.0f;
      #pragma unroll
      for (int j=0;j<5;j++) de[k][j] = 0.0f;
    }
    #pragma unroll
    for (int h=0;h<5;h++){
      #pragma unroll
      for (int k=0;k<8;k++) en[h][k] = 0.0f;
    }
  }

  float s[5];
  #pragma unroll
  for (int j=0;j<5;j++) s[j] = s_enc[j];

  for (int t=0; t<LL; t++){
    // --- u_v = relu(Eg_de[v]@s + c_v); out row t; partial xe ---  (R0 ordering)
    float px[5] = {0,0,0,0,0};
    float o[8];
    #pragma unroll
    for (int k=0;k<8;k++){
      float u = cb[k];
      #pragma unroll
      for (int j=0;j<5;j++) u += de[k][j]*s[j];
      u = fmaxf(u, 0.0f);
      o[k] = u;
      #pragma unroll
      for (int h=0;h<5;h++) px[h] += u*en[h][k];
    }
    f32x4 oa = {o[0], o[1], o[2], o[3]};
    f32x4 ob = {o[4], o[5], o[6], o[7]};
    if (act){
      f32x4* po = (f32x4*)(out + (size_t)t*VSZ + v0);
      po[0] = oa; po[1] = ob;
    }
    if (t == LL-1) break;   // last row needs no new state

    // --- intra-wave reduce ---
    #pragma unroll
    for (int m=1;m<64;m<<=1){
      #pragma unroll
      for (int h=0;h<5;h++) px[h] += __shfl_xor(px[h], m, 64);
    }

    // --- publish: 5 self-tagged u64 words ---
    const unsigned long long tg = (unsigned long long)(t+1);
    if (lane == 0){
      unsigned long long* wp = slots + ((size_t)(t&1)*64 + slot_id)*8;
      #pragma unroll
      for (int j=0;j<5;j++)
        __hip_atomic_store(wp+j, (tg<<32) | (unsigned long long)__float_as_uint(px[j]),
                           __ATOMIC_RELAXED, __HIP_MEMORY_SCOPE_AGENT);
    }

    // --- poll all 64 slots (lane <-> slot), parity double-buffered ---
    const unsigned long long* rp = slots + ((size_t)(t&1)*64 + lane)*8;
    unsigned long long w0,w1,w2,w3,w4;
    for(;;){
      w0 = __hip_atomic_load(rp+0, __ATOMIC_RELAXED, __HIP_MEMORY_SCOPE_AGENT);
      w1 = __hip_atomic_load(rp+1, __ATOMIC_RELAXED, __HIP_MEMORY_SCOPE_AGENT);
      w2 = __hip_atomic_load(rp+2, __ATOMIC_RELAXED, __HIP_MEMORY_SCOPE_AGENT);
      w3 = __hip_atomic_load(rp+3, __ATOMIC_RELAXED, __HIP_MEMORY_SCOPE_AGENT);
      w4 = __hip_atomic_load(rp+4, __ATOMIC_RELAXED, __HIP_MEMORY_SCOPE_AGENT);
      bool ok = ((w0>>32)==tg) & ((w1>>32)==tg) & ((w2>>32)==tg)
              & ((w3>>32)==tg) & ((w4>>32)==tg);
      if (__all(ok)) break;
    }
    float xe[5];
    xe[0] = __uint_as_float((unsigned)w0);
    xe[1] = __uint_as_float((unsigned)w1);
    xe[2] = __uint_as_float((unsigned)w2);
    xe[3] = __uint_as_float((unsigned)w3);
    xe[4] = __uint_as_float((unsigned)w4);
    #pragma unroll
    for (int m=1;m<64;m<<=1){
      #pragma unroll
      for (int j=0;j<5;j++) xe[j] += __shfl_xor(xe[j], m, 64);
    }

    // --- GRU update (redundant per wave; bitwise identical everywhere) ---
    bool conv;
    gru_step_exact(xe, s, conv, Wr, U1r, U2r, bb);

    // --- exact fixed point: all remaining rows are bit-identical to row t ---
    if (conv){
      if (act){
        for (int r = t+1; r < LL; ++r){
          f32x4* po = (f32x4*)(out + (size_t)r*VSZ + v0);
          po[0] = oa; po[1] = ob;
        }
      }
      break;
    }
  }
}

extern "C" void kernel_launch(void* const* d_in, const int* in_sizes, int n_in,
                              void* d_out, int out_size, void* d_ws, size_t ws_size,
                              hipStream_t stream)
{
  const float* x     = (const float*)d_in[0];
  // d_in[1] = l (==1024), fixed by problem shape
  const float* Eg_en = (const float*)d_in[2];
  const float* Eg_de = (const float*)d_in[3];
  const float* cg_de = (const float*)d_in[4];
  const float* Wg_en = (const float*)d_in[5];
  const float* Ug_en = (const float*)d_in[6];
  const float* bg_en = (const float*)d_in[7];
  const float* Wg_de = (const float*)d_in[8];
  const float* Ug_de = (const float*)d_in[9];
  const float* bg_de = (const float*)d_in[10];
  float* out = (float*)d_out;

  float* ws      = (float*)d_ws;
  float* pre_all = ws;             // 1024*16 = 16384 floats
  float* s_enc   = ws + 16384;     // 5 floats (pad to 64)
  float* slots_f = ws + 16448;     // 2048 floats = 8KB: [2][64][8] u64
  unsigned long long* slots = (unsigned long long*)slots_f;

  matmul_pre<<<dim3(TT), dim3(256), 0, stream>>>(x, Eg_en, Wg_en, bg_en, pre_all);
  enc_kernel<<<dim3(1), dim3(64), 0, stream>>>(pre_all, s_enc, slots_f, Ug_en);
  dec_kernel<<<dim3(16), dim3(256), 0, stream>>>(Eg_en, Eg_de, cg_de,
                                                 Wg_de, Ug_de, bg_de,
                                                 s_enc, slots, out);
}

// Round 4
// 187.533 us; speedup vs baseline: 22.4103x; 2.0633x over previous
//
#include <hip/hip_runtime.h>

#define VSZ 32000
#define TT 1024
#define LL 1024
#define NCH 64          // encoder chunks
#define CHL 16          // steps per chunk (NCH*CHL == TT)

typedef float f32x4 __attribute__((ext_vector_type(4)));

// ---------- fast activations (f32; saturate EXACTLY to 0/1/±1 for |x| large) ----------
__device__ __forceinline__ float fast_sigmoid(float x){
  return __builtin_amdgcn_rcpf(1.0f + __expf(-x));
}
__device__ __forceinline__ float fast_tanh(float x){
  float e = __expf(2.0f*x);
  return 1.0f - 2.0f*__builtin_amdgcn_rcpf(e + 1.0f);
}

__device__ __forceinline__ float rl(float v, int l){
  return __uint_as_float((unsigned)__builtin_amdgcn_readlane((int)__float_as_uint(v), l));
}

// ---------- 15-lane GRU weight load: lane g*5+i owns gate (g,i) ----------
__device__ __forceinline__ void load_gru_w(const float* __restrict__ W,
                                           const float* __restrict__ U,
                                           const float* __restrict__ b,
                                           int lane, float Wr[5], float U1r[5], float U2r[5], float& bb)
{
  int g = lane / 5;
  int i = lane - g*5;
  bool okl = (lane < 15);
  int base = okl ? (g*25 + i*5) : 0;
  int bidx = okl ? (g*5 + i) : 0;
  #pragma unroll
  for (int j=0;j<5;j++){
    float w  = W[base + j];
    float u  = U[base + j];
    float u2 = U[50 + i*5 + j];
    Wr[j]  = okl ? w : 0.0f;
    U1r[j] = (okl && g < 2) ? u  : 0.0f;
    U2r[j] = (okl && g == 2) ? u2 : 0.0f;
  }
  bb = okl ? b[bidx] : 0.0f;
}

// exact-form GRU step: s' = z*s + (1-z)*c  (z==1.0 -> s'==s bitwise)
__device__ __forceinline__ void gru_step_exact(const float xe[5], float s[5], bool& conv,
                                               const float Wr[5], const float U1r[5],
                                               const float U2r[5], float bb)
{
  float acc = bb;
  #pragma unroll
  for (int j=0;j<5;j++) acc += Wr[j]*xe[j];
  #pragma unroll
  for (int j=0;j<5;j++) acc += U1r[j]*s[j];
  float zr = fast_sigmoid(acc);               // z lanes 0-4, r lanes 5-9
  float rr[5];
  #pragma unroll
  for (int j=0;j<5;j++) rr[j] = rl(zr, 5+j);
  float acc2 = acc;
  #pragma unroll
  for (int j=0;j<5;j++) acc2 += U2r[j]*(s[j]*rr[j]);
  float cv = fast_tanh(acc2);                 // c lanes 10-14
  conv = true;
  #pragma unroll
  for (int j=0;j<5;j++){
    float zj = rl(zr, j);
    float cj = rl(cv, 10+j);
    float ns = zj*s[j] + (1.0f - zj)*cj;
    conv = conv && (__float_as_uint(ns) == __float_as_uint(s[j]));
    s[j] = ns;
  }
}

// enc chunk step: pre already includes b + W@xe; identical op order to R3's enc step
__device__ __forceinline__ void enc_step(float pre, float s[5],
                                         const float U1r[5], const float U2r[5])
{
  float a0 = U1r[0]*s[0] + U1r[1]*s[1];
  float a1 = U1r[2]*s[2] + U1r[3]*s[3];
  float acc = pre + a0 + a1 + U1r[4]*s[4];
  float zr = fast_sigmoid(acc);
  float rr[5];
  #pragma unroll
  for (int j=0;j<5;j++) rr[j] = rl(zr, 5+j);
  float acc2 = acc;
  #pragma unroll
  for (int j=0;j<5;j++) acc2 += U2r[j]*(s[j]*rr[j]);
  float cv = fast_tanh(acc2);
  #pragma unroll
  for (int j=0;j<5;j++){
    float zj = rl(zr, j);
    float cj = rl(cv, 10+j);
    s[j] = zj*s[j] + (1.0f - zj)*cj;
  }
}

// ---------- kernel A: pre_all[t][k] = b[k] + W_en[k]@(x[t]@Eg_en.T); block 0 clears enc slots ----------
__global__ __launch_bounds__(256) void matmul_pre(const float* __restrict__ x,
                                                  const float* __restrict__ Eg_en,
                                                  const float* __restrict__ W,
                                                  const float* __restrict__ b,
                                                  float* __restrict__ pre_all,
                                                  float* __restrict__ eslots_f) // 1024 floats
{
  const int t = blockIdx.x;
  const int tid = threadIdx.x;
  const int lane = tid & 63, wave = tid >> 6;
  if (t == 0){
    #pragma unroll
    for (int k=0;k<4;k++) eslots_f[k*256 + tid] = 0.0f;
  }
  const f32x4* xr = (const f32x4*)(x + (size_t)t*VSZ);
  float acc[5] = {0,0,0,0,0};
  for (int j = tid; j < VSZ/4; j += 256){
    f32x4 xv = xr[j];
    #pragma unroll
    for (int h=0;h<5;h++){
      f32x4 ev = ((const f32x4*)(Eg_en + (size_t)h*VSZ))[j];
      acc[h] += xv.x*ev.x + xv.y*ev.y + xv.z*ev.z + xv.w*ev.w;
    }
  }
  #pragma unroll
  for (int m=1;m<64;m<<=1){
    #pragma unroll
    for (int h=0;h<5;h++) acc[h] += __shfl_xor(acc[h], m, 64);
  }
  __shared__ float part[4][5];
  __shared__ float xe_s[5];
  if (lane == 0){
    #pragma unroll
    for (int h=0;h<5;h++) part[wave][h] = acc[h];
  }
  __syncthreads();
  if (tid < 5) xe_s[tid] = part[0][tid] + part[1][tid] + part[2][tid] + part[3][tid];
  __syncthreads();
  if (tid < 15){
    int g = tid/5, i = tid - g*5;
    float p = b[g*5+i];
    #pragma unroll
    for (int j=0;j<5;j++) p += W[g*25 + i*5 + j] * xe_s[j];
    pre_all[t*16 + tid] = p;
  }
}

// ---------- kernel B: parallel-in-time encoder. 64 WGs x 1 wave; chunk w = steps [w*16,(w+1)*16) ----------
// Pass p: run chunk from input = prev pass output of chunk w-1 (chunk 0 from true 0).
// Stop when ALL chunks' outputs are bitwise equal to their previous-pass outputs -> chain is
// self-consistent -> bitwise identical to the sequential scan. Also clears decoder slots.
__global__ void enc_kernel(const float* __restrict__ pre_all,
                           float* __restrict__ s_enc,
                           float* __restrict__ dslots_f,            // 2048 floats (dec slots) to clear
                           unsigned long long* __restrict__ eslots, // [64][8] u64
                           const float* __restrict__ U)
{
  const int w = blockIdx.x;      // chunk id, 0..63
  const int lane = threadIdx.x;  // 0..63
  // clear decoder slots (runs before dec_kernel by stream order)
  { int idx = w*64 + lane; if (idx < 2048) dslots_f[idx] = 0.0f; }

  int g = lane/5, i = lane - g*5;
  bool okl = (lane < 15);
  float U1r[5], U2r[5];
  #pragma unroll
  for (int j=0;j<5;j++){
    int base = okl ? (g*25 + i*5) : 0;
    float u  = U[base + j];
    float u2 = U[50 + i*5 + j];
    U1r[j] = (okl && g < 2) ? u  : 0.0f;
    U2r[j] = (okl && g == 2) ? u2 : 0.0f;
  }

  // my chunk's pre values: lane k<15 holds gate k's pre for each of the 16 steps
  float prc[CHL];
  #pragma unroll
  for (int k=0;k<CHL;k++) prc[k] = okl ? pre_all[(w*CHL + k)*16 + lane] : 0.0f;

  float s_in[5] = {0,0,0,0,0};
  float prev[5] = {0,0,0,0,0};
  unsigned p = 0;
  for(;;){
    p++;
    float s[5];
    #pragma unroll
    for (int j=0;j<5;j++) s[j] = s_in[j];
    #pragma unroll
    for (int k=0;k<CHL;k++) enc_step(prc[k], s, U1r, U2r);

    bool stable = (p > 1);
    #pragma unroll
    for (int j=0;j<5;j++)
      stable = stable && (__float_as_uint(s[j]) == __float_as_uint(prev[j]));
    #pragma unroll
    for (int j=0;j<5;j++) prev[j] = s[j];

    // publish: tag hi32 = (p<<1)|stable
    const unsigned long long hi = ((unsigned long long)((p<<1) | (stable?1u:0u))) << 32;
    if (lane == 0){
      unsigned long long* wp = eslots + (size_t)w*8;
      #pragma unroll
      for (int j=0;j<5;j++)
        __hip_atomic_store(wp+j, hi | (unsigned long long)__float_as_uint(s[j]),
                           __ATOMIC_RELAXED, __HIP_MEMORY_SCOPE_AGENT);
    }

    // poll: lane l watches slot l until it carries pass p
    const unsigned long long* rp = eslots + (size_t)lane*8;
    unsigned long long w0,w1,w2,w3,w4;
    for(;;){
      w0 = __hip_atomic_load(rp+0, __ATOMIC_RELAXED, __HIP_MEMORY_SCOPE_AGENT);
      w1 = __hip_atomic_load(rp+1, __ATOMIC_RELAXED, __HIP_MEMORY_SCOPE_AGENT);
      w2 = __hip_atomic_load(rp+2, __ATOMIC_RELAXED, __HIP_MEMORY_SCOPE_AGENT);
      w3 = __hip_atomic_load(rp+3, __ATOMIC_RELAXED, __HIP_MEMORY_SCOPE_AGENT);
      w4 = __hip_atomic_load(rp+4, __ATOMIC_RELAXED, __HIP_MEMORY_SCOPE_AGENT);
      bool ok = ((unsigned)(w0>>33)==p) & ((unsigned)(w1>>33)==p) & ((unsigned)(w2>>33)==p)
              & ((unsigned)(w3>>33)==p) & ((unsigned)(w4>>33)==p);
      if (__all(ok)) break;
    }
    bool slot_stable = ((w0>>32)&1ull) != 0;
    bool gstable = __all(slot_stable);

    float xin[5];
    xin[0] = __uint_as_float((unsigned)w0);
    xin[1] = __uint_as_float((unsigned)w1);
    xin[2] = __uint_as_float((unsigned)w2);
    xin[3] = __uint_as_float((unsigned)w3);
    xin[4] = __uint_as_float((unsigned)w4);

    if (gstable){
      if (w == 0 && lane == 0){
        #pragma unroll
        for (int j=0;j<5;j++) s_enc[j] = rl(xin[j], 63);   // chunk 63 output = final state
      }
      break;
    }
    if (w > 0){
      #pragma unroll
      for (int j=0;j<5;j++) s_in[j] = rl(xin[j], w-1);
    }
  }
}

// ---------- kernel C: decoder with exact fixed-point early exit (unchanged from R3) ----------
__global__ __launch_bounds__(256, 1) void dec_kernel(
    const float* __restrict__ Eg_en, const float* __restrict__ Eg_de,
    const float* __restrict__ cg_de,
    const float* __restrict__ W, const float* __restrict__ U, const float* __restrict__ b,
    const float* __restrict__ s_enc,
    unsigned long long* __restrict__ slots,   // [2 parities][64 slots][8 u64]
    float* __restrict__ out)
{
  const int wg = blockIdx.x;
  const int tid = threadIdx.x;
  const int lane = tid & 63;
  const int wave = tid >> 6;
  const int slot_id = wg*4 + wave;

  float Wr[5], U1r[5], U2r[5], bb;
  load_gru_w(W, U, b, lane, Wr, U1r, U2r, bb);

  const bool act = (tid < 250);              // 250*8 = 2000 v's per WG
  const int v0 = wg*2000 + tid*8;
  float de[8][5], en[5][8], cb[8];
  if (act){
    #pragma unroll
    for (int k=0;k<8;k++){
      #pragma unroll
      for (int j=0;j<5;j++) de[k][j] = Eg_de[(v0+k)*5 + j];
      cb[k] = cg_de[v0+k];
    }
    #pragma unroll
    for (int h=0;h<5;h++){
      #pragma unroll
      for (int k=0;k<8;k++) en[h][k] = Eg_en[h*VSZ + v0 + k];
    }
  } else {
    #pragma unroll
    for (int k=0;k<8;k++){
      cb[k] = 0.0f;
      #pragma unroll
      for (int j=0;j<5;j++) de[k][j] = 0.0f;
    }
    #pragma unroll
    for (int h=0;h<5;h++){
      #pragma unroll
      for (int k=0;k<8;k++) en[h][k] = 0.0f;
    }
  }

  float s[5];
  #pragma unroll
  for (int j=0;j<5;j++) s[j] = s_enc[j];

  for (int t=0; t<LL; t++){
    float px[5] = {0,0,0,0,0};
    float o[8];
    #pragma unroll
    for (int k=0;k<8;k++){
      float u = cb[k];
      #pragma unroll
      for (int j=0;j<5;j++) u += de[k][j]*s[j];
      u = fmaxf(u, 0.0f);
      o[k] = u;
      #pragma unroll
      for (int h=0;h<5;h++) px[h] += u*en[h][k];
    }
    f32x4 oa = {o[0], o[1], o[2], o[3]};
    f32x4 ob = {o[4], o[5], o[6], o[7]};
    if (act){
      f32x4* po = (f32x4*)(out + (size_t)t*VSZ + v0);
      po[0] = oa; po[1] = ob;
    }
    if (t == LL-1) break;

    #pragma unroll
    for (int m=1;m<64;m<<=1){
      #pragma unroll
      for (int h=0;h<5;h++) px[h] += __shfl_xor(px[h], m, 64);
    }

    const unsigned long long tg = (unsigned long long)(t+1);
    if (lane == 0){
      unsigned long long* wp = slots + ((size_t)(t&1)*64 + slot_id)*8;
      #pragma unroll
      for (int j=0;j<5;j++)
        __hip_atomic_store(wp+j, (tg<<32) | (unsigned long long)__float_as_uint(px[j]),
                           __ATOMIC_RELAXED, __HIP_MEMORY_SCOPE_AGENT);
    }

    const unsigned long long* rp = slots + ((size_t)(t&1)*64 + lane)*8;
    unsigned long long w0,w1,w2,w3,w4;
    for(;;){
      w0 = __hip_atomic_load(rp+0, __ATOMIC_RELAXED, __HIP_MEMORY_SCOPE_AGENT);
      w1 = __hip_atomic_load(rp+1, __ATOMIC_RELAXED, __HIP_MEMORY_SCOPE_AGENT);
      w2 = __hip_atomic_load(rp+2, __ATOMIC_RELAXED, __HIP_MEMORY_SCOPE_AGENT);
      w3 = __hip_atomic_load(rp+3, __ATOMIC_RELAXED, __HIP_MEMORY_SCOPE_AGENT);
      w4 = __hip_atomic_load(rp+4, __ATOMIC_RELAXED, __HIP_MEMORY_SCOPE_AGENT);
      bool ok = ((w0>>32)==tg) & ((w1>>32)==tg) & ((w2>>32)==tg)
              & ((w3>>32)==tg) & ((w4>>32)==tg);
      if (__all(ok)) break;
    }
    float xe[5];
    xe[0] = __uint_as_float((unsigned)w0);
    xe[1] = __uint_as_float((unsigned)w1);
    xe[2] = __uint_as_float((unsigned)w2);
    xe[3] = __uint_as_float((unsigned)w3);
    xe[4] = __uint_as_float((unsigned)w4);
    #pragma unroll
    for (int m=1;m<64;m<<=1){
      #pragma unroll
      for (int j=0;j<5;j++) xe[j] += __shfl_xor(xe[j], m, 64);
    }

    bool conv;
    gru_step_exact(xe, s, conv, Wr, U1r, U2r, bb);

    if (conv){
      if (act){
        for (int r = t+1; r < LL; ++r){
          f32x4* po = (f32x4*)(out + (size_t)r*VSZ + v0);
          po[0] = oa; po[1] = ob;
        }
      }
      break;
    }
  }
}

extern "C" void kernel_launch(void* const* d_in, const int* in_sizes, int n_in,
                              void* d_out, int out_size, void* d_ws, size_t ws_size,
                              hipStream_t stream)
{
  const float* x     = (const float*)d_in[0];
  // d_in[1] = l (==1024), fixed by problem shape
  const float* Eg_en = (const float*)d_in[2];
  const float* Eg_de = (const float*)d_in[3];
  const float* cg_de = (const float*)d_in[4];
  const float* Wg_en = (const float*)d_in[5];
  const float* Ug_en = (const float*)d_in[6];
  const float* bg_en = (const float*)d_in[7];
  const float* Wg_de = (const float*)d_in[8];
  const float* Ug_de = (const float*)d_in[9];
  const float* bg_de = (const float*)d_in[10];
  float* out = (float*)d_out;

  float* ws       = (float*)d_ws;
  float* pre_all  = ws;             // 1024*16 = 16384 floats
  float* s_enc    = ws + 16384;     // 5 floats (pad to 64)
  float* eslots_f = ws + 16448;     // 1024 floats = 4KB: [64][8] u64
  float* dslots_f = ws + 17472;     // 2048 floats = 8KB: [2][64][8] u64
  unsigned long long* eslots = (unsigned long long*)eslots_f;
  unsigned long long* dslots = (unsigned long long*)dslots_f;

  matmul_pre<<<dim3(TT), dim3(256), 0, stream>>>(x, Eg_en, Wg_en, bg_en, pre_all, eslots_f);
  enc_kernel<<<dim3(NCH), dim3(64), 0, stream>>>(pre_all, s_enc, dslots_f, eslots, Ug_en);
  dec_kernel<<<dim3(16), dim3(256), 0, stream>>>(Eg_en, Eg_de, cg_de,
                                                 Wg_de, Ug_de, bg_de,
                                                 s_enc, dslots, out);
}

// Round 5
// 94.091 us; speedup vs baseline: 44.6659x; 1.9931x over previous
//
#include <hip/hip_runtime.h>

#define VSZ 32000
#define TT 1024
#define LL 1024
#define NCH 64          // encoder chunks
#define CHL 16          // steps per chunk (NCH*CHL == TT)

typedef float f32x4 __attribute__((ext_vector_type(4)));

// ---------- fast activations (f32; saturate EXACTLY to 0/1/±1 for |x| large) ----------
__device__ __forceinline__ float fast_sigmoid(float x){
  return __builtin_amdgcn_rcpf(1.0f + __expf(-x));
}
__device__ __forceinline__ float fast_tanh(float x){
  float e = __expf(2.0f*x);
  return 1.0f - 2.0f*__builtin_amdgcn_rcpf(e + 1.0f);
}

__device__ __forceinline__ float rl(float v, int l){
  return __uint_as_float((unsigned)__builtin_amdgcn_readlane((int)__float_as_uint(v), l));
}

// ---------- 15-lane GRU weight load: lane g*5+i owns gate (g,i) ----------
__device__ __forceinline__ void load_gru_w(const float* __restrict__ W,
                                           const float* __restrict__ U,
                                           const float* __restrict__ b,
                                           int lane, float Wr[5], float U1r[5], float U2r[5], float& bb)
{
  int g = lane / 5;
  int i = lane - g*5;
  bool okl = (lane < 15);
  int base = okl ? (g*25 + i*5) : 0;
  int bidx = okl ? (g*5 + i) : 0;
  #pragma unroll
  for (int j=0;j<5;j++){
    float w  = W[base + j];
    float u  = U[base + j];
    float u2 = U[50 + i*5 + j];
    Wr[j]  = okl ? w : 0.0f;
    U1r[j] = (okl && g < 2) ? u  : 0.0f;
    U2r[j] = (okl && g == 2) ? u2 : 0.0f;
  }
  bb = okl ? b[bidx] : 0.0f;
}

// exact-form GRU step: s' = z*s + (1-z)*c  (z==1.0 -> s'==s bitwise)
__device__ __forceinline__ void gru_step_exact(const float xe[5], float s[5], bool& conv,
                                               const float Wr[5], const float U1r[5],
                                               const float U2r[5], float bb)
{
  float acc = bb;
  #pragma unroll
  for (int j=0;j<5;j++) acc += Wr[j]*xe[j];
  #pragma unroll
  for (int j=0;j<5;j++) acc += U1r[j]*s[j];
  float zr = fast_sigmoid(acc);               // z lanes 0-4, r lanes 5-9
  float rr[5];
  #pragma unroll
  for (int j=0;j<5;j++) rr[j] = rl(zr, 5+j);
  float acc2 = acc;
  #pragma unroll
  for (int j=0;j<5;j++) acc2 += U2r[j]*(s[j]*rr[j]);
  float cv = fast_tanh(acc2);                 // c lanes 10-14
  conv = true;
  #pragma unroll
  for (int j=0;j<5;j++){
    float zj = rl(zr, j);
    float cj = rl(cv, 10+j);
    float ns = zj*s[j] + (1.0f - zj)*cj;
    conv = conv && (__float_as_uint(ns) == __float_as_uint(s[j]));
    s[j] = ns;
  }
}

// enc chunk step: pre already includes b + W@xe
__device__ __forceinline__ void enc_step(float pre, float s[5],
                                         const float U1r[5], const float U2r[5])
{
  float a0 = U1r[0]*s[0] + U1r[1]*s[1];
  float a1 = U1r[2]*s[2] + U1r[3]*s[3];
  float acc = pre + a0 + a1 + U1r[4]*s[4];
  float zr = fast_sigmoid(acc);
  float rr[5];
  #pragma unroll
  for (int j=0;j<5;j++) rr[j] = rl(zr, 5+j);
  float acc2 = acc;
  #pragma unroll
  for (int j=0;j<5;j++) acc2 += U2r[j]*(s[j]*rr[j]);
  float cv = fast_tanh(acc2);
  #pragma unroll
  for (int j=0;j<5;j++){
    float zj = rl(zr, j);
    float cj = rl(cv, 10+j);
    s[j] = zj*s[j] + (1.0f - zj)*cj;
  }
}

// ---------- kernel A: pre_all[t][k] = b[k] + W_en[k]@(x[t]@Eg_en.T); block 0 clears enc slots ----------
__global__ __launch_bounds__(256) void matmul_pre(const float* __restrict__ x,
                                                  const float* __restrict__ Eg_en,
                                                  const float* __restrict__ W,
                                                  const float* __restrict__ b,
                                                  float* __restrict__ pre_all,
                                                  float* __restrict__ eslots_f) // 1024 floats
{
  const int t = blockIdx.x;
  const int tid = threadIdx.x;
  const int lane = tid & 63, wave = tid >> 6;
  if (t == 0){
    #pragma unroll
    for (int k=0;k<4;k++) eslots_f[k*256 + tid] = 0.0f;
  }
  const f32x4* xr = (const f32x4*)(x + (size_t)t*VSZ);
  float acc[5] = {0,0,0,0,0};
  for (int j = tid; j < VSZ/4; j += 256){
    f32x4 xv = xr[j];
    #pragma unroll
    for (int h=0;h<5;h++){
      f32x4 ev = ((const f32x4*)(Eg_en + (size_t)h*VSZ))[j];
      acc[h] += xv.x*ev.x + xv.y*ev.y + xv.z*ev.z + xv.w*ev.w;
    }
  }
  #pragma unroll
  for (int m=1;m<64;m<<=1){
    #pragma unroll
    for (int h=0;h<5;h++) acc[h] += __shfl_xor(acc[h], m, 64);
  }
  __shared__ float part[4][5];
  __shared__ float xe_s[5];
  if (lane == 0){
    #pragma unroll
    for (int h=0;h<5;h++) part[wave][h] = acc[h];
  }
  __syncthreads();
  if (tid < 5) xe_s[tid] = part[0][tid] + part[1][tid] + part[2][tid] + part[3][tid];
  __syncthreads();
  if (tid < 15){
    int g = tid/5, i = tid - g*5;
    float p = b[g*5+i];
    #pragma unroll
    for (int j=0;j<5;j++) p += W[g*25 + i*5 + j] * xe_s[j];
    pre_all[t*16 + tid] = p;
  }
}

// ---------- kernel B: parallel-in-time encoder (64 WGs x 1 wave), exact bitwise verification ----------
__global__ void enc_kernel(const float* __restrict__ pre_all,
                           float* __restrict__ s_enc,
                           float* __restrict__ dslots_f,            // 2048 floats (dec slots) to clear
                           unsigned long long* __restrict__ eslots, // [64][8] u64
                           const float* __restrict__ U)
{
  const int w = blockIdx.x;      // chunk id, 0..63
  const int lane = threadIdx.x;  // 0..63
  { int idx = w*64 + lane; if (idx < 2048) dslots_f[idx] = 0.0f; }

  int g = lane/5, i = lane - g*5;
  bool okl = (lane < 15);
  float U1r[5], U2r[5];
  #pragma unroll
  for (int j=0;j<5;j++){
    int base = okl ? (g*25 + i*5) : 0;
    float u  = U[base + j];
    float u2 = U[50 + i*5 + j];
    U1r[j] = (okl && g < 2) ? u  : 0.0f;
    U2r[j] = (okl && g == 2) ? u2 : 0.0f;
  }

  float prc[CHL];
  #pragma unroll
  for (int k=0;k<CHL;k++) prc[k] = okl ? pre_all[(w*CHL + k)*16 + lane] : 0.0f;

  float s_in[5] = {0,0,0,0,0};
  float prev[5] = {0,0,0,0,0};
  unsigned p = 0;
  for(;;){
    p++;
    float s[5];
    #pragma unroll
    for (int j=0;j<5;j++) s[j] = s_in[j];
    #pragma unroll
    for (int k=0;k<CHL;k++) enc_step(prc[k], s, U1r, U2r);

    bool stable = (p > 1);
    #pragma unroll
    for (int j=0;j<5;j++)
      stable = stable && (__float_as_uint(s[j]) == __float_as_uint(prev[j]));
    #pragma unroll
    for (int j=0;j<5;j++) prev[j] = s[j];

    const unsigned long long hi = ((unsigned long long)((p<<1) | (stable?1u:0u))) << 32;
    if (lane == 0){
      unsigned long long* wp = eslots + (size_t)w*8;
      #pragma unroll
      for (int j=0;j<5;j++)
        __hip_atomic_store(wp+j, hi | (unsigned long long)__float_as_uint(s[j]),
                           __ATOMIC_RELAXED, __HIP_MEMORY_SCOPE_AGENT);
    }

    const unsigned long long* rp = eslots + (size_t)lane*8;
    unsigned long long w0,w1,w2,w3,w4;
    for(;;){
      w0 = __hip_atomic_load(rp+0, __ATOMIC_RELAXED, __HIP_MEMORY_SCOPE_AGENT);
      w1 = __hip_atomic_load(rp+1, __ATOMIC_RELAXED, __HIP_MEMORY_SCOPE_AGENT);
      w2 = __hip_atomic_load(rp+2, __ATOMIC_RELAXED, __HIP_MEMORY_SCOPE_AGENT);
      w3 = __hip_atomic_load(rp+3, __ATOMIC_RELAXED, __HIP_MEMORY_SCOPE_AGENT);
      w4 = __hip_atomic_load(rp+4, __ATOMIC_RELAXED, __HIP_MEMORY_SCOPE_AGENT);
      bool ok = ((unsigned)(w0>>33)==p) & ((unsigned)(w1>>33)==p) & ((unsigned)(w2>>33)==p)
              & ((unsigned)(w3>>33)==p) & ((unsigned)(w4>>33)==p);
      if (__all(ok)) break;
    }
    bool slot_stable = ((w0>>32)&1ull) != 0;
    bool gstable = __all(slot_stable);

    float xin[5];
    xin[0] = __uint_as_float((unsigned)w0);
    xin[1] = __uint_as_float((unsigned)w1);
    xin[2] = __uint_as_float((unsigned)w2);
    xin[3] = __uint_as_float((unsigned)w3);
    xin[4] = __uint_as_float((unsigned)w4);

    if (gstable){
      if (w == 0 && lane == 0){
        #pragma unroll
        for (int j=0;j<5;j++) s_enc[j] = rl(xin[j], 63);   // chunk 63 output = final state
      }
      break;
    }
    if (w > 0){
      #pragma unroll
      for (int j=0;j<5;j++) s_in[j] = rl(xin[j], w-1);
    }
  }
}

// ---------- kernel C: decoder; writes rows 0..t*, records t_conv, NO bulk fill ----------
__global__ __launch_bounds__(256, 1) void dec_kernel(
    const float* __restrict__ Eg_en, const float* __restrict__ Eg_de,
    const float* __restrict__ cg_de,
    const float* __restrict__ W, const float* __restrict__ U, const float* __restrict__ b,
    const float* __restrict__ s_enc,
    unsigned long long* __restrict__ slots,   // [2 parities][64 slots][8 u64]
    float* __restrict__ out,
    int* __restrict__ t_conv_out)
{
  const int wg = blockIdx.x;
  const int tid = threadIdx.x;
  const int lane = tid & 63;
  const int wave = tid >> 6;
  const int slot_id = wg*4 + wave;

  float Wr[5], U1r[5], U2r[5], bb;
  load_gru_w(W, U, b, lane, Wr, U1r, U2r, bb);

  const bool act = (tid < 250);              // 250*8 = 2000 v's per WG
  const int v0 = wg*2000 + tid*8;
  float de[8][5], en[5][8], cb[8];
  if (act){
    #pragma unroll
    for (int k=0;k<8;k++){
      #pragma unroll
      for (int j=0;j<5;j++) de[k][j] = Eg_de[(v0+k)*5 + j];
      cb[k] = cg_de[v0+k];
    }
    #pragma unroll
    for (int h=0;h<5;h++){
      #pragma unroll
      for (int k=0;k<8;k++) en[h][k] = Eg_en[h*VSZ + v0 + k];
    }
  } else {
    #pragma unroll
    for (int k=0;k<8;k++){
      cb[k] = 0.0f;
      #pragma unroll
      for (int j=0;j<5;j++) de[k][j] = 0.0f;
    }
    #pragma unroll
    for (int h=0;h<5;h++){
      #pragma unroll
      for (int k=0;k<8;k++) en[h][k] = 0.0f;
    }
  }

  float s[5];
  #pragma unroll
  for (int j=0;j<5;j++) s[j] = s_enc[j];

  for (int t=0; t<LL; t++){
    float px[5] = {0,0,0,0,0};
    float o[8];
    #pragma unroll
    for (int k=0;k<8;k++){
      float u = cb[k];
      #pragma unroll
      for (int j=0;j<5;j++) u += de[k][j]*s[j];
      u = fmaxf(u, 0.0f);
      o[k] = u;
      #pragma unroll
      for (int h=0;h<5;h++) px[h] += u*en[h][k];
    }
    if (act){
      f32x4* po = (f32x4*)(out + (size_t)t*VSZ + v0);
      f32x4 oa = {o[0], o[1], o[2], o[3]};
      f32x4 ob = {o[4], o[5], o[6], o[7]};
      po[0] = oa; po[1] = ob;
    }
    if (t == LL-1){
      if (wg == 0 && tid == 0) *t_conv_out = LL-1;
      break;
    }

    #pragma unroll
    for (int m=1;m<64;m<<=1){
      #pragma unroll
      for (int h=0;h<5;h++) px[h] += __shfl_xor(px[h], m, 64);
    }

    const unsigned long long tg = (unsigned long long)(t+1);
    if (lane == 0){
      unsigned long long* wp = slots + ((size_t)(t&1)*64 + slot_id)*8;
      #pragma unroll
      for (int j=0;j<5;j++)
        __hip_atomic_store(wp+j, (tg<<32) | (unsigned long long)__float_as_uint(px[j]),
                           __ATOMIC_RELAXED, __HIP_MEMORY_SCOPE_AGENT);
    }

    const unsigned long long* rp = slots + ((size_t)(t&1)*64 + lane)*8;
    unsigned long long w0,w1,w2,w3,w4;
    for(;;){
      w0 = __hip_atomic_load(rp+0, __ATOMIC_RELAXED, __HIP_MEMORY_SCOPE_AGENT);
      w1 = __hip_atomic_load(rp+1, __ATOMIC_RELAXED, __HIP_MEMORY_SCOPE_AGENT);
      w2 = __hip_atomic_load(rp+2, __ATOMIC_RELAXED, __HIP_MEMORY_SCOPE_AGENT);
      w3 = __hip_atomic_load(rp+3, __ATOMIC_RELAXED, __HIP_MEMORY_SCOPE_AGENT);
      w4 = __hip_atomic_load(rp+4, __ATOMIC_RELAXED, __HIP_MEMORY_SCOPE_AGENT);
      bool ok = ((w0>>32)==tg) & ((w1>>32)==tg) & ((w2>>32)==tg)
              & ((w3>>32)==tg) & ((w4>>32)==tg);
      if (__all(ok)) break;
    }
    float xe[5];
    xe[0] = __uint_as_float((unsigned)w0);
    xe[1] = __uint_as_float((unsigned)w1);
    xe[2] = __uint_as_float((unsigned)w2);
    xe[3] = __uint_as_float((unsigned)w3);
    xe[4] = __uint_as_float((unsigned)w4);
    #pragma unroll
    for (int m=1;m<64;m<<=1){
      #pragma unroll
      for (int j=0;j<5;j++) xe[j] += __shfl_xor(xe[j], m, 64);
    }

    bool conv;
    gru_step_exact(xe, s, conv, Wr, U1r, U2r, bb);

    if (conv){
      if (wg == 0 && tid == 0) *t_conv_out = t;   // rows t+1.. == row t bitwise
      break;
    }
  }
}

// ---------- kernel D: full-chip broadcast fill of rows t_conv+1..LL-1 ----------
__global__ __launch_bounds__(256) void fill_kernel(const int* __restrict__ t_conv_p,
                                                   float* __restrict__ out)
{
  const int tc = *t_conv_p;
  const int r = blockIdx.y;
  if (r <= tc) return;
  const int tid = threadIdx.x;
  if (tid >= 250) return;
  const int off = blockIdx.x*2000 + tid*8;
  const f32x4* src = (const f32x4*)(out + (size_t)tc*VSZ + off);
  f32x4 a = src[0], b = src[1];
  f32x4* dst = (f32x4*)(out + (size_t)r*VSZ + off);
  dst[0] = a; dst[1] = b;
}

extern "C" void kernel_launch(void* const* d_in, const int* in_sizes, int n_in,
                              void* d_out, int out_size, void* d_ws, size_t ws_size,
                              hipStream_t stream)
{
  const float* x     = (const float*)d_in[0];
  // d_in[1] = l (==1024), fixed by problem shape
  const float* Eg_en = (const float*)d_in[2];
  const float* Eg_de = (const float*)d_in[3];
  const float* cg_de = (const float*)d_in[4];
  const float* Wg_en = (const float*)d_in[5];
  const float* Ug_en = (const float*)d_in[6];
  const float* bg_en = (const float*)d_in[7];
  const float* Wg_de = (const float*)d_in[8];
  const float* Ug_de = (const float*)d_in[9];
  const float* bg_de = (const float*)d_in[10];
  float* out = (float*)d_out;

  float* ws       = (float*)d_ws;
  float* pre_all  = ws;             // 1024*16 = 16384 floats
  float* s_enc    = ws + 16384;     // 5 floats (pad to 64)
  int*   t_conv   = (int*)(ws + 16448); // 1 int (pad to 64)
  float* eslots_f = ws + 16512;     // 1024 floats = 4KB: [64][8] u64
  float* dslots_f = ws + 17536;     // 2048 floats = 8KB: [2][64][8] u64
  unsigned long long* eslots = (unsigned long long*)eslots_f;
  unsigned long long* dslots = (unsigned long long*)dslots_f;

  matmul_pre<<<dim3(TT), dim3(256), 0, stream>>>(x, Eg_en, Wg_en, bg_en, pre_all, eslots_f);
  enc_kernel<<<dim3(NCH), dim3(64), 0, stream>>>(pre_all, s_enc, dslots_f, eslots, Ug_en);
  dec_kernel<<<dim3(16), dim3(256), 0, stream>>>(Eg_en, Eg_de, cg_de,
                                                 Wg_de, Ug_de, bg_de,
                                                 s_enc, dslots, out, t_conv);
  fill_kernel<<<dim3(16, LL), dim3(256), 0, stream>>>(t_conv, out);
}

// Round 6
// 79.931 us; speedup vs baseline: 52.5789x; 1.1772x over previous
//
#include <hip/hip_runtime.h>

#define VSZ 32000
#define TT 1024
#define LL 1024
#define NCH 64          // encoder chunks
#define CHL 16          // steps per chunk (NCH*CHL == TT)
#define TROW 4          // x rows per matmul_pre block

typedef float f32x4 __attribute__((ext_vector_type(4)));

// ---------- fast activations (f32; saturate EXACTLY to 0/1/±1 for |x| large) ----------
__device__ __forceinline__ float fast_sigmoid(float x){
  return __builtin_amdgcn_rcpf(1.0f + __expf(-x));
}
__device__ __forceinline__ float fast_tanh(float x){
  float e = __expf(2.0f*x);
  return 1.0f - 2.0f*__builtin_amdgcn_rcpf(e + 1.0f);
}

__device__ __forceinline__ float rl(float v, int l){
  return __uint_as_float((unsigned)__builtin_amdgcn_readlane((int)__float_as_uint(v), l));
}

// ---------- 15-lane GRU weight load: lane g*5+i owns gate (g,i) ----------
__device__ __forceinline__ void load_gru_w(const float* __restrict__ W,
                                           const float* __restrict__ U,
                                           const float* __restrict__ b,
                                           int lane, float Wr[5], float U1r[5], float U2r[5], float& bb)
{
  int g = lane / 5;
  int i = lane - g*5;
  bool okl = (lane < 15);
  int base = okl ? (g*25 + i*5) : 0;
  int bidx = okl ? (g*5 + i) : 0;
  #pragma unroll
  for (int j=0;j<5;j++){
    float w  = W[base + j];
    float u  = U[base + j];
    float u2 = U[50 + i*5 + j];
    Wr[j]  = okl ? w : 0.0f;
    U1r[j] = (okl && g < 2) ? u  : 0.0f;
    U2r[j] = (okl && g == 2) ? u2 : 0.0f;
  }
  bb = okl ? b[bidx] : 0.0f;
}

// exact-form GRU step: s' = z*s + (1-z)*c  (z==1.0 -> s'==s bitwise)
__device__ __forceinline__ void gru_step_exact(const float xe[5], float s[5], bool& conv,
                                               const float Wr[5], const float U1r[5],
                                               const float U2r[5], float bb)
{
  float acc = bb;
  #pragma unroll
  for (int j=0;j<5;j++) acc += Wr[j]*xe[j];
  #pragma unroll
  for (int j=0;j<5;j++) acc += U1r[j]*s[j];
  float zr = fast_sigmoid(acc);               // z lanes 0-4, r lanes 5-9
  float rr[5];
  #pragma unroll
  for (int j=0;j<5;j++) rr[j] = rl(zr, 5+j);
  float acc2 = acc;
  #pragma unroll
  for (int j=0;j<5;j++) acc2 += U2r[j]*(s[j]*rr[j]);
  float cv = fast_tanh(acc2);                 // c lanes 10-14
  conv = true;
  #pragma unroll
  for (int j=0;j<5;j++){
    float zj = rl(zr, j);
    float cj = rl(cv, 10+j);
    float ns = zj*s[j] + (1.0f - zj)*cj;
    conv = conv && (__float_as_uint(ns) == __float_as_uint(s[j]));
    s[j] = ns;
  }
}

// enc chunk step: pre already includes b + W@xe
__device__ __forceinline__ void enc_step(float pre, float s[5],
                                         const float U1r[5], const float U2r[5])
{
  float a0 = U1r[0]*s[0] + U1r[1]*s[1];
  float a1 = U1r[2]*s[2] + U1r[3]*s[3];
  float acc = pre + a0 + a1 + U1r[4]*s[4];
  float zr = fast_sigmoid(acc);
  float rr[5];
  #pragma unroll
  for (int j=0;j<5;j++) rr[j] = rl(zr, 5+j);
  float acc2 = acc;
  #pragma unroll
  for (int j=0;j<5;j++) acc2 += U2r[j]*(s[j]*rr[j]);
  float cv = fast_tanh(acc2);
  #pragma unroll
  for (int j=0;j<5;j++){
    float zj = rl(zr, j);
    float cj = rl(cv, 10+j);
    s[j] = zj*s[j] + (1.0f - zj)*cj;
  }
}

// ---------- kernel A: pre_all[t][k] = b[k] + W_en[k]@(x[t]@Eg_en.T) ----------
// T-tiled: TROW rows per block; Eg_en loaded once per j per block (L2 traffic /TROW).
// Per-(t,h) accumulation order is BITWISE IDENTICAL to the untiled version.
__global__ __launch_bounds__(256) void matmul_pre(const float* __restrict__ x,
                                                  const float* __restrict__ Eg_en,
                                                  const float* __restrict__ W,
                                                  const float* __restrict__ b,
                                                  float* __restrict__ pre_all,
                                                  float* __restrict__ eslots_f) // 1024 floats
{
  const int t0 = blockIdx.x * TROW;
  const int tid = threadIdx.x;
  const int lane = tid & 63, wave = tid >> 6;
  if (blockIdx.x == 0){
    #pragma unroll
    for (int k=0;k<4;k++) eslots_f[k*256 + tid] = 0.0f;
  }
  float acc[TROW][5];
  #pragma unroll
  for (int r=0;r<TROW;r++)
    #pragma unroll
    for (int h=0;h<5;h++) acc[r][h] = 0.0f;

  #pragma unroll 2
  for (int j = tid; j < VSZ/4; j += 256){
    f32x4 ev[5];
    #pragma unroll
    for (int h=0;h<5;h++) ev[h] = ((const f32x4*)(Eg_en + (size_t)h*VSZ))[j];
    #pragma unroll
    for (int r=0;r<TROW;r++){
      f32x4 xv = ((const f32x4*)(x + (size_t)(t0+r)*VSZ))[j];
      #pragma unroll
      for (int h=0;h<5;h++)
        acc[r][h] += xv.x*ev[h].x + xv.y*ev[h].y + xv.z*ev[h].z + xv.w*ev[h].w;
    }
  }
  #pragma unroll
  for (int m=1;m<64;m<<=1){
    #pragma unroll
    for (int r=0;r<TROW;r++)
      #pragma unroll
      for (int h=0;h<5;h++) acc[r][h] += __shfl_xor(acc[r][h], m, 64);
  }
  __shared__ float part[4][TROW][5];
  __shared__ float xe_s[TROW][5];
  if (lane == 0){
    #pragma unroll
    for (int r=0;r<TROW;r++)
      #pragma unroll
      for (int h=0;h<5;h++) part[wave][r][h] = acc[r][h];
  }
  __syncthreads();
  if (tid < TROW*5){
    int r = tid/5, h = tid - r*5;
    xe_s[r][h] = part[0][r][h] + part[1][r][h] + part[2][r][h] + part[3][r][h];
  }
  __syncthreads();
  if (tid < TROW*16){
    int r = tid >> 4, k = tid & 15;
    if (k < 15){
      int g = k/5, i = k - g*5;
      float p = b[g*5+i];
      #pragma unroll
      for (int j=0;j<5;j++) p += W[g*25 + i*5 + j] * xe_s[r][j];
      pre_all[(t0+r)*16 + k] = p;
    }
  }
}

// ---------- kernel B: parallel-in-time encoder (64 WGs x 1 wave), exact bitwise verification ----------
__global__ void enc_kernel(const float* __restrict__ pre_all,
                           float* __restrict__ s_enc,
                           float* __restrict__ dslots_f,            // 2048 floats (dec slots) to clear
                           unsigned long long* __restrict__ eslots, // [64][8] u64
                           const float* __restrict__ U)
{
  const int w = blockIdx.x;      // chunk id, 0..63
  const int lane = threadIdx.x;  // 0..63
  { int idx = w*64 + lane; if (idx < 2048) dslots_f[idx] = 0.0f; }

  int g = lane/5, i = lane - g*5;
  bool okl = (lane < 15);
  float U1r[5], U2r[5];
  #pragma unroll
  for (int j=0;j<5;j++){
    int base = okl ? (g*25 + i*5) : 0;
    float u  = U[base + j];
    float u2 = U[50 + i*5 + j];
    U1r[j] = (okl && g < 2) ? u  : 0.0f;
    U2r[j] = (okl && g == 2) ? u2 : 0.0f;
  }

  float prc[CHL];
  #pragma unroll
  for (int k=0;k<CHL;k++) prc[k] = okl ? pre_all[(w*CHL + k)*16 + lane] : 0.0f;

  float s_in[5] = {0,0,0,0,0};
  float prev[5] = {0,0,0,0,0};
  unsigned p = 0;
  for(;;){
    p++;
    float s[5];
    #pragma unroll
    for (int j=0;j<5;j++) s[j] = s_in[j];
    #pragma unroll
    for (int k=0;k<CHL;k++) enc_step(prc[k], s, U1r, U2r);

    bool stable = (p > 1);
    #pragma unroll
    for (int j=0;j<5;j++)
      stable = stable && (__float_as_uint(s[j]) == __float_as_uint(prev[j]));
    #pragma unroll
    for (int j=0;j<5;j++) prev[j] = s[j];

    const unsigned long long hi = ((unsigned long long)((p<<1) | (stable?1u:0u))) << 32;
    if (lane == 0){
      unsigned long long* wp = eslots + (size_t)w*8;
      #pragma unroll
      for (int j=0;j<5;j++)
        __hip_atomic_store(wp+j, hi | (unsigned long long)__float_as_uint(s[j]),
                           __ATOMIC_RELAXED, __HIP_MEMORY_SCOPE_AGENT);
    }

    const unsigned long long* rp = eslots + (size_t)lane*8;
    unsigned long long w0,w1,w2,w3,w4;
    for(;;){
      w0 = __hip_atomic_load(rp+0, __ATOMIC_RELAXED, __HIP_MEMORY_SCOPE_AGENT);
      w1 = __hip_atomic_load(rp+1, __ATOMIC_RELAXED, __HIP_MEMORY_SCOPE_AGENT);
      w2 = __hip_atomic_load(rp+2, __ATOMIC_RELAXED, __HIP_MEMORY_SCOPE_AGENT);
      w3 = __hip_atomic_load(rp+3, __ATOMIC_RELAXED, __HIP_MEMORY_SCOPE_AGENT);
      w4 = __hip_atomic_load(rp+4, __ATOMIC_RELAXED, __HIP_MEMORY_SCOPE_AGENT);
      bool ok = ((unsigned)(w0>>33)==p) & ((unsigned)(w1>>33)==p) & ((unsigned)(w2>>33)==p)
              & ((unsigned)(w3>>33)==p) & ((unsigned)(w4>>33)==p);
      if (__all(ok)) break;
    }
    bool slot_stable = ((w0>>32)&1ull) != 0;
    bool gstable = __all(slot_stable);

    float xin[5];
    xin[0] = __uint_as_float((unsigned)w0);
    xin[1] = __uint_as_float((unsigned)w1);
    xin[2] = __uint_as_float((unsigned)w2);
    xin[3] = __uint_as_float((unsigned)w3);
    xin[4] = __uint_as_float((unsigned)w4);

    if (gstable){
      if (w == 0 && lane == 0){
        #pragma unroll
        for (int j=0;j<5;j++) s_enc[j] = rl(xin[j], 63);   // chunk 63 output = final state
      }
      break;
    }
    if (w > 0){
      #pragma unroll
      for (int j=0;j<5;j++) s_in[j] = rl(xin[j], w-1);
    }
  }
}

// ---------- kernel C: decoder; writes rows 0..t*, records t_conv ----------
__global__ __launch_bounds__(256, 1) void dec_kernel(
    const float* __restrict__ Eg_en, const float* __restrict__ Eg_de,
    const float* __restrict__ cg_de,
    const float* __restrict__ W, const float* __restrict__ U, const float* __restrict__ b,
    const float* __restrict__ s_enc,
    unsigned long long* __restrict__ slots,   // [2 parities][64 slots][8 u64]
    float* __restrict__ out,
    int* __restrict__ t_conv_out)
{
  const int wg = blockIdx.x;
  const int tid = threadIdx.x;
  const int lane = tid & 63;
  const int wave = tid >> 6;
  const int slot_id = wg*4 + wave;

  float Wr[5], U1r[5], U2r[5], bb;
  load_gru_w(W, U, b, lane, Wr, U1r, U2r, bb);

  const bool act = (tid < 250);              // 250*8 = 2000 v's per WG
  const int v0 = wg*2000 + tid*8;
  float de[8][5], en[5][8], cb[8];
  if (act){
    #pragma unroll
    for (int k=0;k<8;k++){
      #pragma unroll
      for (int j=0;j<5;j++) de[k][j] = Eg_de[(v0+k)*5 + j];
      cb[k] = cg_de[v0+k];
    }
    #pragma unroll
    for (int h=0;h<5;h++){
      #pragma unroll
      for (int k=0;k<8;k++) en[h][k] = Eg_en[h*VSZ + v0 + k];
    }
  } else {
    #pragma unroll
    for (int k=0;k<8;k++){
      cb[k] = 0.0f;
      #pragma unroll
      for (int j=0;j<5;j++) de[k][j] = 0.0f;
    }
    #pragma unroll
    for (int h=0;h<5;h++){
      #pragma unroll
      for (int k=0;k<8;k++) en[h][k] = 0.0f;
    }
  }

  float s[5];
  #pragma unroll
  for (int j=0;j<5;j++) s[j] = s_enc[j];

  for (int t=0; t<LL; t++){
    float px[5] = {0,0,0,0,0};
    float o[8];
    #pragma unroll
    for (int k=0;k<8;k++){
      float u = cb[k];
      #pragma unroll
      for (int j=0;j<5;j++) u += de[k][j]*s[j];
      u = fmaxf(u, 0.0f);
      o[k] = u;
      #pragma unroll
      for (int h=0;h<5;h++) px[h] += u*en[h][k];
    }
    if (act){
      f32x4* po = (f32x4*)(out + (size_t)t*VSZ + v0);
      f32x4 oa = {o[0], o[1], o[2], o[3]};
      f32x4 ob = {o[4], o[5], o[6], o[7]};
      po[0] = oa; po[1] = ob;
    }
    if (t == LL-1){
      if (wg == 0 && tid == 0) *t_conv_out = LL-1;
      break;
    }

    #pragma unroll
    for (int m=1;m<64;m<<=1){
      #pragma unroll
      for (int h=0;h<5;h++) px[h] += __shfl_xor(px[h], m, 64);
    }

    const unsigned long long tg = (unsigned long long)(t+1);
    if (lane == 0){
      unsigned long long* wp = slots + ((size_t)(t&1)*64 + slot_id)*8;
      #pragma unroll
      for (int j=0;j<5;j++)
        __hip_atomic_store(wp+j, (tg<<32) | (unsigned long long)__float_as_uint(px[j]),
                           __ATOMIC_RELAXED, __HIP_MEMORY_SCOPE_AGENT);
    }

    const unsigned long long* rp = slots + ((size_t)(t&1)*64 + lane)*8;
    unsigned long long w0,w1,w2,w3,w4;
    for(;;){
      w0 = __hip_atomic_load(rp+0, __ATOMIC_RELAXED, __HIP_MEMORY_SCOPE_AGENT);
      w1 = __hip_atomic_load(rp+1, __ATOMIC_RELAXED, __HIP_MEMORY_SCOPE_AGENT);
      w2 = __hip_atomic_load(rp+2, __ATOMIC_RELAXED, __HIP_MEMORY_SCOPE_AGENT);
      w3 = __hip_atomic_load(rp+3, __ATOMIC_RELAXED, __HIP_MEMORY_SCOPE_AGENT);
      w4 = __hip_atomic_load(rp+4, __ATOMIC_RELAXED, __HIP_MEMORY_SCOPE_AGENT);
      bool ok = ((w0>>32)==tg) & ((w1>>32)==tg) & ((w2>>32)==tg)
              & ((w3>>32)==tg) & ((w4>>32)==tg);
      if (__all(ok)) break;
    }
    float xe[5];
    xe[0] = __uint_as_float((unsigned)w0);
    xe[1] = __uint_as_float((unsigned)w1);
    xe[2] = __uint_as_float((unsigned)w2);
    xe[3] = __uint_as_float((unsigned)w3);
    xe[4] = __uint_as_float((unsigned)w4);
    #pragma unroll
    for (int m=1;m<64;m<<=1){
      #pragma unroll
      for (int j=0;j<5;j++) xe[j] += __shfl_xor(xe[j], m, 64);
    }

    bool conv;
    gru_step_exact(xe, s, conv, Wr, U1r, U2r, bb);

    if (conv){
      if (wg == 0 && tid == 0) *t_conv_out = t;   // rows t+1.. == row t bitwise
      break;
    }
  }
}

// ---------- kernel D: full-chip broadcast fill of rows t_conv+1..LL-1 ----------
__global__ __launch_bounds__(256) void fill_kernel(const int* __restrict__ t_conv_p,
                                                   float* __restrict__ out)
{
  const int tc = *t_conv_p;
  const int r = blockIdx.y;
  if (r <= tc) return;
  const int tid = threadIdx.x;
  if (tid >= 250) return;
  const int off = blockIdx.x*2000 + tid*8;
  const f32x4* src = (const f32x4*)(out + (size_t)tc*VSZ + off);
  f32x4 a = src[0], b = src[1];
  f32x4* dst = (f32x4*)(out + (size_t)r*VSZ + off);
  dst[0] = a; dst[1] = b;
}

extern "C" void kernel_launch(void* const* d_in, const int* in_sizes, int n_in,
                              void* d_out, int out_size, void* d_ws, size_t ws_size,
                              hipStream_t stream)
{
  const float* x     = (const float*)d_in[0];
  // d_in[1] = l (==1024), fixed by problem shape
  const float* Eg_en = (const float*)d_in[2];
  const float* Eg_de = (const float*)d_in[3];
  const float* cg_de = (const float*)d_in[4];
  const float* Wg_en = (const float*)d_in[5];
  const float* Ug_en = (const float*)d_in[6];
  const float* bg_en = (const float*)d_in[7];
  const float* Wg_de = (const float*)d_in[8];
  const float* Ug_de = (const float*)d_in[9];
  const float* bg_de = (const float*)d_in[10];
  float* out = (float*)d_out;

  float* ws       = (float*)d_ws;
  float* pre_all  = ws;             // 1024*16 = 16384 floats
  float* s_enc    = ws + 16384;     // 5 floats (pad to 64)
  int*   t_conv   = (int*)(ws + 16448); // 1 int (pad to 64)
  float* eslots_f = ws + 16512;     // 1024 floats = 4KB: [64][8] u64
  float* dslots_f = ws + 17536;     // 2048 floats = 8KB: [2][64][8] u64
  unsigned long long* eslots = (unsigned long long*)eslots_f;
  unsigned long long* dslots = (unsigned long long*)dslots_f;

  matmul_pre<<<dim3(TT/TROW), dim3(256), 0, stream>>>(x, Eg_en, Wg_en, bg_en, pre_all, eslots_f);
  enc_kernel<<<dim3(NCH), dim3(64), 0, stream>>>(pre_all, s_enc, dslots_f, eslots, Ug_en);
  dec_kernel<<<dim3(16), dim3(256), 0, stream>>>(Eg_en, Eg_de, cg_de,
                                                 Wg_de, Ug_de, bg_de,
                                                 s_enc, dslots, out, t_conv);
  fill_kernel<<<dim3(16, LL), dim3(256), 0, stream>>>(t_conv, out);
}